// Round 19
// baseline (292.844 us; speedup 1.0000x reference)
//
#include <hip/hip_runtime.h>
#include <math.h>

#define QL 2048
#define HISTN 2048
#define KLEN 4096
#define NH 12
#define NKVH 2
#define HD 128
#define HID 1536
#define NQKV 2048   // 1536 q + 256 k + 256 v
#define VTROWS 144  // 128 d + 1 ones + 15 zeros (ones now unused by attn)
#define QSCALE 0.08838834764831845f  // 1/sqrt(128)

typedef unsigned short u16;
typedef short bf16x8 __attribute__((ext_vector_type(8)));
typedef float f32x4 __attribute__((ext_vector_type(4)));

__device__ __forceinline__ u16 f2bf(float f) {
  union { float f; unsigned u; } v; v.f = f;
  unsigned r = v.u + 0x7FFFu + ((v.u >> 16) & 1u);
  return (u16)(r >> 16);
}
__device__ __forceinline__ float bf2f(u16 h) {
  union { unsigned u; float f; } v; v.u = ((unsigned)h) << 16; return v.f;
}
__device__ __forceinline__ unsigned cvt_pk_bf16(float lo, float hi) {
  unsigned d;
  asm("v_cvt_pk_bf16_f32 %0, %1, %2" : "=v"(d) : "v"(lo), "v"(hi));
  return d;
}

// ---------- split_T tile helper: W[K][N] 64x64 tile -> Bt[N][K] hi/lo -------
__device__ __forceinline__ void split_T_tile(const float* __restrict__ W,
    u16* __restrict__ BtH, u16* __restrict__ BtL, int K, int N, int k0, int n0,
    int t, float (*T)[65]) {
  const int r = t >> 4, c = (t & 15) * 4;
#pragma unroll
  for (int p = 0; p < 4; ++p) {
    float4 v = *(const float4*)&W[(size_t)(k0 + p * 16 + r) * N + n0 + c];
    T[p * 16 + r][c + 0] = v.x; T[p * 16 + r][c + 1] = v.y;
    T[p * 16 + r][c + 2] = v.z; T[p * 16 + r][c + 3] = v.w;
  }
  __syncthreads();
  const int rr = t >> 2, cc0 = (t & 3) * 16;
#pragma unroll
  for (int i4 = 0; i4 < 4; ++i4) {
    float f0 = T[cc0 + i4 * 4 + 0][rr];
    float f1 = T[cc0 + i4 * 4 + 1][rr];
    float f2 = T[cc0 + i4 * 4 + 2][rr];
    float f3 = T[cc0 + i4 * 4 + 3][rr];
    ushort4 h, l;
    h.x = f2bf(f0); l.x = f2bf(f0 - bf2f(h.x));
    h.y = f2bf(f1); l.y = f2bf(f1 - bf2f(h.y));
    h.z = f2bf(f2); l.z = f2bf(f2 - bf2f(h.z));
    h.w = f2bf(f3); l.w = f2bf(f3 - bf2f(h.w));
    size_t off = (size_t)(n0 + rr) * K + k0 + cc0 + i4 * 4;
    *(ushort4*)&BtH[off] = h;
    *(ushort4*)&BtL[off] = l;
  }
}

// ---------- fused prep: splitf(x) + split_T(Wq,Wk,Wv,Wo) + bias concat ------
__global__ __launch_bounds__(256) void prep(
    const float* __restrict__ x,  const float* __restrict__ Wq,
    const float* __restrict__ Wk, const float* __restrict__ Wv,
    const float* __restrict__ Wo, const float* __restrict__ bq,
    const float* __restrict__ bk, const float* __restrict__ bv,
    u16* __restrict__ xh, u16* __restrict__ xl,
    u16* __restrict__ WqkvH, u16* __restrict__ WqkvL,
    u16* __restrict__ WoH, u16* __restrict__ WoL, float* __restrict__ bcat) {
  __shared__ float T[64][65];
  const int bx = blockIdx.x, t = threadIdx.x;
  if (bx < 3072) {                       // splitf: 786432 float4s
    int i = bx * 256 + t;
    float4 v = ((const float4*)x)[i];
    ushort4 h, l;
    h.x = f2bf(v.x); l.x = f2bf(v.x - bf2f(h.x));
    h.y = f2bf(v.y); l.y = f2bf(v.y - bf2f(h.y));
    h.z = f2bf(v.z); l.z = f2bf(v.z - bf2f(h.z));
    h.w = f2bf(v.w); l.w = f2bf(v.w - bf2f(h.w));
    ((ushort4*)xh)[i] = h;
    ((ushort4*)xl)[i] = l;
  } else if (bx < 3648) {                // Wq: 24 n-tiles x 24 k-tiles
    int b = bx - 3072;
    split_T_tile(Wq, WqkvH, WqkvL, HID, HID, (b / 24) * 64, (b % 24) * 64, t, T);
  } else if (bx < 3744) {                // Wk: 4 x 24
    int b = bx - 3648;
    split_T_tile(Wk, WqkvH + (size_t)HID * HID, WqkvL + (size_t)HID * HID,
                 HID, 256, (b / 4) * 64, (b % 4) * 64, t, T);
  } else if (bx < 3840) {                // Wv: 4 x 24
    int b = bx - 3744;
    split_T_tile(Wv, WqkvH + (size_t)(HID + 256) * HID, WqkvL + (size_t)(HID + 256) * HID,
                 HID, 256, (b / 4) * 64, (b % 4) * 64, t, T);
  } else if (bx < 4416) {                // Wo: 24 x 24
    int b = bx - 3840;
    split_T_tile(Wo, WoH, WoL, HID, HID, (b / 24) * 64, (b % 24) * 64, t, T);
  } else {                               // bias concat: 8 blocks
    int i = (bx - 4416) * 256 + t;
    bcat[i] = (i < HID) ? bq[i] : (i < HID + 256 ? bk[i - HID] : bv[i - HID - 256]);
  }
}

// ------------- bf16x3 GEMM, 128x64 tile, 4 waves, LDS-staged ----------------
// v1 structure (verified 296.9/298.3/295.2/294.2/292.4 us config): stage via
// global_load_lds w=16, linear LDS dest + source XOR-swizzle, serial
// 2-barrier K-loop. 48 KB LDS; independent blocks/CU provide the latency
// overlap (m114) that the BK=32-dbuf (v2) and 128x128 (v3) variants
// destroyed (+31/+28 us measured). No setprio: harmful on lockstep GEMM (m190).
__global__ __launch_bounds__(256, 2) void gemm3(
    const u16* __restrict__ Ah, const u16* __restrict__ Al,
    const u16* __restrict__ Bh, const u16* __restrict__ Bl,
    const float* __restrict__ bias, float* __restrict__ C,
    int K, int ldc) {
  __shared__ __align__(16) u16 sAh[128 * 64];   // 16 KB, row = 8 x 16B chunks
  __shared__ __align__(16) u16 sAl[128 * 64];   // 16 KB
  __shared__ __align__(16) u16 sBh[64 * 64];    // 8 KB
  __shared__ __align__(16) u16 sBl[64 * 64];    // 8 KB
  const int m0 = blockIdx.y * 128, n0 = blockIdx.x * 64;
  const int t = threadIdx.x, lane = t & 63, w = t >> 6;
  const int quad = lane >> 4, l15 = lane & 15;
  const int wm = w >> 1, wn = w & 1;            // wave tile: 64(M) x 32(N)
  const int l8 = lane >> 3, j8 = lane & 7;      // staging: 8 lanes per row

  f32x4 acc[4][2];
#pragma unroll
  for (int mt = 0; mt < 4; ++mt)
#pragma unroll
    for (int nt = 0; nt < 2; ++nt) acc[mt][nt] = (f32x4){0.f, 0.f, 0.f, 0.f};

  for (int k0 = 0; k0 < K; k0 += 64) {
    if (k0) __syncthreads();                    // waves done reading prev tile
#pragma unroll
    for (int i = 0; i < 4; ++i) {               // A hi/lo: 128 rows
      int r = (i * 4 + w) * 8 + l8;
      size_t goff = (size_t)(m0 + r) * K + k0 + ((j8 ^ (r & 7)) << 3);
      __builtin_amdgcn_global_load_lds(
          (const __attribute__((address_space(1))) void*)(Ah + goff),
          (__attribute__((address_space(3))) void*)&sAh[(i * 4 + w) * 512], 16, 0, 0);
      __builtin_amdgcn_global_load_lds(
          (const __attribute__((address_space(1))) void*)(Al + goff),
          (__attribute__((address_space(3))) void*)&sAl[(i * 4 + w) * 512], 16, 0, 0);
    }
#pragma unroll
    for (int i = 0; i < 2; ++i) {               // B hi/lo: 64 rows
      int r = (i * 4 + w) * 8 + l8;
      size_t goff = (size_t)(n0 + r) * K + k0 + ((j8 ^ (r & 7)) << 3);
      __builtin_amdgcn_global_load_lds(
          (const __attribute__((address_space(1))) void*)(Bh + goff),
          (__attribute__((address_space(3))) void*)&sBh[(i * 4 + w) * 512], 16, 0, 0);
      __builtin_amdgcn_global_load_lds(
          (const __attribute__((address_space(1))) void*)(Bl + goff),
          (__attribute__((address_space(3))) void*)&sBl[(i * 4 + w) * 512], 16, 0, 0);
    }
    __syncthreads();                            // compiler drains vmcnt: ready
#pragma unroll
    for (int kk = 0; kk < 2; ++kk) {
      bf16x8 aH[4], aL[4], bH[2], bL[2];
#pragma unroll
      for (int mt = 0; mt < 4; ++mt) {
        int r = wm * 64 + mt * 16 + l15;
        int addr = r * 64 + ((((kk << 2) + quad) ^ (r & 7)) << 3);
        aH[mt] = *(const bf16x8*)&sAh[addr];
        aL[mt] = *(const bf16x8*)&sAl[addr];
      }
#pragma unroll
      for (int nt = 0; nt < 2; ++nt) {
        int r = wn * 32 + nt * 16 + l15;
        int addr = r * 64 + ((((kk << 2) + quad) ^ (r & 7)) << 3);
        bH[nt] = *(const bf16x8*)&sBh[addr];
        bL[nt] = *(const bf16x8*)&sBl[addr];
      }
#pragma unroll
      for (int mt = 0; mt < 4; ++mt)
#pragma unroll
        for (int nt = 0; nt < 2; ++nt) {
          acc[mt][nt] = __builtin_amdgcn_mfma_f32_16x16x32_bf16(aH[mt], bH[nt], acc[mt][nt], 0, 0, 0);
          acc[mt][nt] = __builtin_amdgcn_mfma_f32_16x16x32_bf16(aH[mt], bL[nt], acc[mt][nt], 0, 0, 0);
          acc[mt][nt] = __builtin_amdgcn_mfma_f32_16x16x32_bf16(aL[mt], bH[nt], acc[mt][nt], 0, 0, 0);
        }
    }
  }
#pragma unroll
  for (int nt = 0; nt < 2; ++nt) {
    int col = n0 + wn * 32 + nt * 16 + l15;
    float bv = bias ? bias[col] : 0.f;
#pragma unroll
    for (int mt = 0; mt < 4; ++mt)
#pragma unroll
      for (int reg = 0; reg < 4; ++reg) {
        int row = m0 + wm * 64 + mt * 16 + quad * 4 + reg;
        C[(size_t)row * ldc + col] = acc[mt][nt][reg] + bv;
      }
  }
}

// ---------- fused post: rope_q + build_k + build_vt -------------------------
__global__ __launch_bounds__(256) void post(
    const float* __restrict__ qkv, const float* __restrict__ k_hist,
    const float* __restrict__ v_hist, const float* __restrict__ cs,
    const float* __restrict__ sn, u16* __restrict__ Qb, u16* __restrict__ Kb,
    u16* __restrict__ Vt) {
  __shared__ u16 T[64][68];
  const int bx = blockIdx.x, t = threadIdx.x;
  if (bx < 1536) {                       // rope_q: NH*QL*16 float4-pairs
    int idx = bx * 256 + t;
    int dp4 = (idx & 15) * 4;
    int q   = (idx >> 4) & 2047;
    int h   = idx >> 15;
    const float* base = qkv + (size_t)q * NQKV + h * HD;
    float4 x1 = *(const float4*)&base[dp4];
    float4 x2 = *(const float4*)&base[dp4 + 64];
    float4 c = *(const float4*)&cs[q * 64 + dp4];
    float4 s = *(const float4*)&sn[q * 64 + dp4];
    u16* ob = Qb + ((size_t)h * QL + q) * HD;
    ushort4 o1, o2;
    o1.x = f2bf((x1.x * c.x - x2.x * s.x) * QSCALE);
    o1.y = f2bf((x1.y * c.y - x2.y * s.y) * QSCALE);
    o1.z = f2bf((x1.z * c.z - x2.z * s.z) * QSCALE);
    o1.w = f2bf((x1.w * c.w - x2.w * s.w) * QSCALE);
    o2.x = f2bf((x1.x * s.x + x2.x * c.x) * QSCALE);
    o2.y = f2bf((x1.y * s.y + x2.y * c.y) * QSCALE);
    o2.z = f2bf((x1.z * s.z + x2.z * c.z) * QSCALE);
    o2.w = f2bf((x1.w * s.w + x2.w * c.w) * QSCALE);
    *(ushort4*)&ob[dp4]      = o1;
    *(ushort4*)&ob[dp4 + 64] = o2;
  } else if (bx < 2048) {                // build_k: NKVH*KLEN*16
    int idx = (bx - 1536) * 256 + t;
    int dp4 = (idx & 15) * 4;
    int tt  = (idx >> 4) & 4095;
    int kvh = idx >> 16;
    u16* ob = Kb + ((size_t)kvh * KLEN + tt) * HD;
    if (tt < HISTN) {
      const float* hb = k_hist + ((size_t)tt * NKVH + kvh) * HD;
      float4 a = *(const float4*)&hb[dp4];
      float4 b = *(const float4*)&hb[dp4 + 64];
      ushort4 o1, o2;
      o1.x = f2bf(a.x); o1.y = f2bf(a.y); o1.z = f2bf(a.z); o1.w = f2bf(a.w);
      o2.x = f2bf(b.x); o2.y = f2bf(b.y); o2.z = f2bf(b.z); o2.w = f2bf(b.w);
      *(ushort4*)&ob[dp4]      = o1;
      *(ushort4*)&ob[dp4 + 64] = o2;
    } else {
      int q = tt - HISTN;
      const float* base = qkv + (size_t)q * NQKV + HID + kvh * HD;
      float4 x1 = *(const float4*)&base[dp4];
      float4 x2 = *(const float4*)&base[dp4 + 64];
      float4 c = *(const float4*)&cs[q * 64 + dp4];
      float4 s = *(const float4*)&sn[q * 64 + dp4];
      ushort4 o1, o2;
      o1.x = f2bf(x1.x * c.x - x2.x * s.x);
      o1.y = f2bf(x1.y * c.y - x2.y * s.y);
      o1.z = f2bf(x1.z * c.z - x2.z * s.z);
      o1.w = f2bf(x1.w * c.w - x2.w * s.w);
      o2.x = f2bf(x1.x * s.x + x2.x * c.x);
      o2.y = f2bf(x1.y * s.y + x2.y * c.y);
      o2.z = f2bf(x1.z * s.z + x2.z * c.z);
      o2.w = f2bf(x1.w * s.w + x2.w * c.w);
      *(ushort4*)&ob[dp4]      = o1;
      *(ushort4*)&ob[dp4 + 64] = o2;
    }
  } else {                               // build_vt: 260 blocks
    int b = bx - 2048;
    int xt = b % 65, rest = b / 65;
    int dh = rest & 1, kvh = rest >> 1;
    if (xt == 64) {                      // rows 128..143: 128=ones, rest zero
      int r0 = 128 + dh * 8;
      u16* base = Vt + ((size_t)kvh * VTROWS) * KLEN;
      for (int i = t; i < 8192; i += 256) {
        int row = r0 + (i >> 10), c4 = (i & 1023) * 4;
        u16 v = (row == 128) ? (u16)0x3F80 : (u16)0;
        ushort4 o4 = {v, v, v, v};
        *(ushort4*)&base[(size_t)row * KLEN + c4] = o4;
      }
      return;
    }
    const int t0 = xt * 64, d0 = dh * 64;
    const int r = t >> 4, c = (t & 15) * 4;
#pragma unroll
    for (int p = 0; p < 4; ++p) {
      int tt = t0 + p * 16 + r;
      float4 v;
      if (tt < HISTN) v = *(const float4*)&v_hist[((size_t)tt * NKVH + kvh) * HD + d0 + c];
      else            v = *(const float4*)&qkv[(size_t)(tt - HISTN) * NQKV + HID + 256 + kvh * HD + d0 + c];
      T[p * 16 + r][c + 0] = f2bf(v.x); T[p * 16 + r][c + 1] = f2bf(v.y);
      T[p * 16 + r][c + 2] = f2bf(v.z); T[p * 16 + r][c + 3] = f2bf(v.w);
    }
    __syncthreads();
    const int dr = t >> 2, cc0 = (t & 3) * 16;
#pragma unroll
    for (int i4 = 0; i4 < 4; ++i4) {
      ushort4 o4;
      o4.x = T[cc0 + i4 * 4 + 0][dr];
      o4.y = T[cc0 + i4 * 4 + 1][dr];
      o4.z = T[cc0 + i4 * 4 + 2][dr];
      o4.w = T[cc0 + i4 * 4 + 3][dr];
      *(ushort4*)&Vt[((size_t)kvh * VTROWS + d0 + dr) * KLEN + t0 + cc0 + i4 * 4] = o4;
    }
  }
}

// -------- attn6: dbuf K/V staging + swapped-QK in-register softmax ----------
// Verified best (292.4/294.2/295.2 us total, attn6 ~104 us): dbuf prefetch,
// swapped-QK in-register softmax (cvt_pk + quad shuffle), transposed oacc
// for coalesced 4x64B atomics, T5 setprio around MFMA clusters (m191).
__global__ __launch_bounds__(384, 3) void attn6(
    const u16* __restrict__ Q, const u16* __restrict__ K,
    const u16* __restrict__ Vt, float* __restrict__ oacc) {
  __shared__ __align__(16) u16 sK[2][64 * 128];  // 2 x 16 KB, swizzled
  __shared__ __align__(16) u16 sV[2][128 * 64];  // 2 x 16 KB, swizzled (rows=d)
  const int bid = blockIdx.x;
  const int kvh   = (bid >> 2) & 1;
  const int qs    = (bid & 3) | ((bid >> 3) << 2);   // 0..255
  const int qt    = qs >> 2, slice = qs & 3;
  const int q0 = qt * 32;
  const int t = threadIdx.x, lane = t & 63, w = t / 64;   // w = head-in-group
  const int h = kvh * 6 + w;
  const int quad = lane >> 4, l15 = lane & 15, q8 = quad * 8;

  const u16* Qg = Q + ((size_t)h * QL + q0) * HD;
  bf16x8 Qf[2][4];
#pragma unroll
  for (int mt = 0; mt < 2; ++mt)
#pragma unroll
    for (int dc = 0; dc < 4; ++dc)
      Qf[mt][dc] = *(const bf16x8*)&Qg[(mt * 16 + l15) * HD + dc * 32 + q8];

  const int nsteps = (q0 + 32 + HISTN + 63) >> 6;
  const int bas = nsteps >> 2, rem = nsteps & 3;
  const int cnt = bas + (slice < rem ? 1 : 0);
  const int s0  = slice * bas + (slice < rem ? slice : rem);

  f32x4 o[2][8];
  float lp[2] = {0.f, 0.f};
#pragma unroll
  for (int mt = 0; mt < 2; ++mt)
#pragma unroll
    for (int dt = 0; dt < 8; ++dt) o[mt][dt] = (f32x4){0.f, 0.f, 0.f, 0.f};

  const u16* Kh = K + (size_t)kvh * KLEN * HD;
  const u16* Vh = Vt + (size_t)kvh * VTROWS * KLEN;
  const int x7 = l15 & 7;

  auto STAGE = [&](int b, int k0) {
    for (int i = w; i < 32; i += 6) {
      if (i < 16) {
        int r = 4 * i + (lane >> 4);        // K row 0..63
        int c = lane & 15;                  // 16B chunk 0..15
        const u16* src = Kh + (size_t)(k0 + r) * HD + ((c ^ (r & 7)) << 3);
        __builtin_amdgcn_global_load_lds(
            (const __attribute__((address_space(1))) void*)src,
            (__attribute__((address_space(3))) void*)&sK[b][i * 512], 16, 0, 0);
      } else {
        int j = i - 16;
        int r = 8 * j + (lane >> 3);        // V d-row 0..127
        int c = lane & 7;                   // 16B chunk 0..7
        const u16* src = Vh + (size_t)r * KLEN + k0 + ((c ^ (r & 7)) << 3);
        __builtin_amdgcn_global_load_lds(
            (const __attribute__((address_space(1))) void*)src,
            (__attribute__((address_space(3))) void*)&sV[b][j * 512], 16, 0, 0);
      }
    }
  };

  int cur = 0;
  STAGE(0, s0 << 6);
  __syncthreads();     // prologue drain: tile s0 ready

  for (int s = s0; s < s0 + cnt; ++s) {
    const int k0 = s << 6;
    if (s + 1 < s0 + cnt) STAGE(cur ^ 1, (s + 1) << 6);   // prefetch next
    f32x4 sc[2][4];
#pragma unroll
    for (int mt = 0; mt < 2; ++mt)
#pragma unroll
      for (int kt = 0; kt < 4; ++kt) sc[mt][kt] = (f32x4){0.f, 0.f, 0.f, 0.f};
    __builtin_amdgcn_s_setprio(1);   // T5: favor this wave during QK MFMA
#pragma unroll
    for (int dc = 0; dc < 4; ++dc) {
      bf16x8 bK[4];
#pragma unroll
      for (int kt = 0; kt < 4; ++kt)
        bK[kt] = *(const bf16x8*)&sK[cur][(kt * 16 + l15) * 128 + (((dc * 4 + quad) ^ x7) << 3)];
#pragma unroll
      for (int mt = 0; mt < 2; ++mt)
#pragma unroll
        for (int kt = 0; kt < 4; ++kt)
          sc[mt][kt] = __builtin_amdgcn_mfma_f32_16x16x32_bf16(bK[kt], Qf[mt][dc], sc[mt][kt], 0, 0, 0);
    }
    __builtin_amdgcn_s_setprio(0);   // back to normal for VALU phase
    if (k0 + 63 - HISTN > q0) {   // causal boundary inside this step
#pragma unroll
      for (int mt = 0; mt < 2; ++mt)
#pragma unroll
        for (int kt = 0; kt < 4; ++kt) {
#pragma unroll
          for (int reg = 0; reg < 4; ++reg) {
            int kg = k0 + kt * 16 + quad * 4 + reg;
            if (kg > q0 + mt * 16 + l15 + HISTN) sc[mt][kt][reg] = -INFINITY;
          }
        }
    }
#pragma unroll
    for (int mt = 0; mt < 2; ++mt)
#pragma unroll
      for (int kt = 0; kt < 4; ++kt)
#pragma unroll
        for (int reg = 0; reg < 4; ++reg) {
          float p = __expf(sc[mt][kt][reg]);
          sc[mt][kt][reg] = p;
          lp[mt] += p;
        }
#pragma unroll
    for (int kc = 0; kc < 2; ++kc) {
      bf16x8 pP[2];
#pragma unroll
      for (int mt = 0; mt < 2; ++mt) {
        const f32x4 pa = sc[mt][kc * 2];
        const f32x4 pb = sc[mt][kc * 2 + 1];
        unsigned A0 = cvt_pk_bf16(pa[0], pa[1]);
        unsigned A1 = cvt_pk_bf16(pa[2], pa[3]);
        unsigned B0 = cvt_pk_bf16(pb[0], pb[1]);
        unsigned B1 = cvt_pk_bf16(pb[2], pb[3]);
        bool hiQ = quad >= 2;
        unsigned s16a = hiQ ? B0 : A0, s16b = hiQ ? B1 : A1;
        unsigned s3a  = hiQ ? A0 : B0, s3b  = hiQ ? A1 : B1;
        unsigned r16a = __shfl_xor(s16a, 16), r16b = __shfl_xor(s16b, 16);
        unsigned r32a = __shfl_xor(s3a, 32),  r32b = __shfl_xor(s3b, 32);
        unsigned r48a = __shfl_xor(s3a, 48),  r48b = __shfl_xor(s3b, 48);
        union { unsigned u[4]; bf16x8 v; } P;
        P.u[0] = quad == 0 ? A0 : quad == 1 ? r48a : quad == 2 ? r32a : r16a;
        P.u[1] = quad == 0 ? A1 : quad == 1 ? r48b : quad == 2 ? r32b : r16b;
        P.u[2] = quad == 0 ? r16a : quad == 1 ? r32a : quad == 2 ? r48a : B0;
        P.u[3] = quad == 0 ? r16b : quad == 1 ? r32b : quad == 2 ? r48b : B1;
        pP[mt] = P.v;
      }
      __builtin_amdgcn_s_setprio(1);   // T5: favor this wave during PV MFMA
#pragma unroll
      for (int dt = 0; dt < 8; ++dt) {
        bf16x8 bV = *(const bf16x8*)&sV[cur][(dt * 16 + l15) * 64 + (((kc * 4 + quad) ^ x7) << 3)];
#pragma unroll
        for (int mt = 0; mt < 2; ++mt)
          o[mt][dt] = __builtin_amdgcn_mfma_f32_16x16x32_bf16(bV, pP[mt], o[mt][dt], 0, 0, 0);
      }
      __builtin_amdgcn_s_setprio(0);
    }
    __syncthreads();   // all waves done with tile cur; prefetch drained+visible
    cur ^= 1;
  }

  // ---- accumulate partials: oacc[h][dv][q] -> coalesced 4x64B per instr ----
  float* ob = oacc + (size_t)h * 132 * QL + q0;
#pragma unroll
  for (int mt = 0; mt < 2; ++mt) {
    lp[mt] += __shfl_xor(lp[mt], 16);
    lp[mt] += __shfl_xor(lp[mt], 32);
    int qc = mt * 16 + l15;
#pragma unroll
    for (int dt = 0; dt < 8; ++dt)
#pragma unroll
      for (int reg = 0; reg < 4; ++reg)
        atomicAdd(&ob[(size_t)(dt * 16 + quad * 4 + reg) * QL + qc], o[mt][dt][reg]);
    if (quad == 0) atomicAdd(&ob[(size_t)128 * QL + qc], lp[mt]);
  }
}

// ---------- attn_norm: LDS transpose [h][dv][q] -> attn[q][HID], /l ---------
__global__ __launch_bounds__(256) void attn_norm(const float* __restrict__ oacc,
    u16* __restrict__ OH, u16* __restrict__ OL) {
  __shared__ float T2[128][33];
  __shared__ float linv[32];
  const int h  = blockIdx.x >> 6;              // 12 x 64 blocks
  const int q0 = (blockIdx.x & 63) * 32;
  const int t  = threadIdx.x;
  const float* base = oacc + (size_t)h * 132 * QL + q0;
  const int col = t & 31, r0 = t >> 5;         // 8 rows per pass, coalesced
#pragma unroll
  for (int pass = 0; pass < 16; ++pass) {
    int row = pass * 8 + r0;
    T2[row][col] = base[(size_t)row * QL + col];
  }
  if (t < 32) linv[t] = 1.f / base[(size_t)128 * QL + t];
  __syncthreads();
  const int ql = t >> 3, d0 = (t & 7) * 16;
  float inv = linv[ql];
  size_t ob = (size_t)(q0 + ql) * HID + h * HD + d0;
#pragma unroll
  for (int j = 0; j < 16; ++j) {
    float val = T2[d0 + j][ql] * inv;
    u16 hv = f2bf(val);
    OH[ob + j] = hv;
    OL[ob + j] = f2bf(val - bf2f(hv));
  }
}

extern "C" void kernel_launch(void* const* d_in, const int* in_sizes, int n_in,
                              void* d_out, int out_size, void* d_ws, size_t ws_size,
                              hipStream_t stream) {
  (void)in_sizes; (void)n_in; (void)out_size; (void)ws_size;
  const float* x      = (const float*)d_in[0];
  const float* Wq     = (const float*)d_in[1];
  const float* bq     = (const float*)d_in[2];
  const float* Wk     = (const float*)d_in[3];
  const float* bk     = (const float*)d_in[4];
  const float* Wv     = (const float*)d_in[5];
  const float* bv     = (const float*)d_in[6];
  const float* Wo     = (const float*)d_in[7];
  const float* k_hist = (const float*)d_in[8];
  const float* v_hist = (const float*)d_in[9];
  const float* fcos   = (const float*)d_in[10];
  const float* fsin   = (const float*)d_in[11];
  float* out = (float*)d_out;

  char* p = (char*)d_ws;
  float* qkv   = (float*)p;  p += (size_t)QL * NQKV * 4;            // 16.78 MB
  u16*   Qb    = (u16*)p;    p += (size_t)NH * QL * HD * 2;
  u16*   Kb    = (u16*)p;    p += (size_t)NKVH * KLEN * HD * 2;
  u16*   Vtb   = (u16*)p;    p += (size_t)NKVH * VTROWS * KLEN * 2;
  u16*   xh    = (u16*)p;    p += (size_t)QL * HID * 2;             // alias attnH
  u16*   xl    = (u16*)p;    p += (size_t)QL * HID * 2;             // alias attnL
  u16*   WqkvH = (u16*)p;    p += (size_t)NQKV * HID * 2;
  u16*   WqkvL = (u16*)p;    p += (size_t)NQKV * HID * 2;
  u16*   WoH   = (u16*)p;    p += (size_t)HID * HID * 2;
  u16*   WoL   = (u16*)p;    p += (size_t)HID * HID * 2;
  float* bcat  = (float*)p;  p += (size_t)NQKV * 4;                 // ~64 MB total
  u16* attnH = xh;  u16* attnL = xl;    // x dead after QKV gemm
  float* oacc = qkv;                    // qkv dead after post; 12x132x2048 f32

  prep<<<4424, 256, 0, stream>>>(x, Wq, Wk, Wv, Wo, bq, bk, bv,
                                 xh, xl, WqkvH, WqkvL, WoH, WoL, bcat);
  gemm3<<<dim3(NQKV / 64, QL / 128), 256, 0, stream>>>(xh, xl, WqkvH, WqkvL, bcat, qkv, HID, NQKV);
  post<<<2308, 256, 0, stream>>>(qkv, k_hist, v_hist, fcos, fsin, Qb, Kb, Vtb);
  hipMemsetAsync(oacc, 0, (size_t)NH * 132 * QL * 4, stream);
  attn6<<<512, 384, 0, stream>>>(Qb, Kb, Vtb, oacc);
  attn_norm<<<768, 256, 0, stream>>>(oacc, attnH, attnL);
  gemm3<<<dim3(HID / 64, QL / 128), 256, 0, stream>>>(attnH, attnL, WoH, WoL, nullptr, out, HID, HID);
}

// Round 20
// 292.075 us; speedup vs baseline: 1.0026x; 1.0026x over previous
//
#include <hip/hip_runtime.h>
#include <math.h>

#define QL 2048
#define HISTN 2048
#define KLEN 4096
#define NH 12
#define NKVH 2
#define HD 128
#define HID 1536
#define NQKV 2048   // 1536 q + 256 k + 256 v
#define VTROWS 144  // 128 d + 1 ones + 15 zeros (ones now unused by attn)
#define QSCALE 0.08838834764831845f  // 1/sqrt(128)

typedef unsigned short u16;
typedef short bf16x8 __attribute__((ext_vector_type(8)));
typedef float f32x4 __attribute__((ext_vector_type(4)));

__device__ __forceinline__ u16 f2bf(float f) {
  union { float f; unsigned u; } v; v.f = f;
  unsigned r = v.u + 0x7FFFu + ((v.u >> 16) & 1u);
  return (u16)(r >> 16);
}
__device__ __forceinline__ float bf2f(u16 h) {
  union { unsigned u; float f; } v; v.u = ((unsigned)h) << 16; return v.f;
}
__device__ __forceinline__ unsigned cvt_pk_bf16(float lo, float hi) {
  unsigned d;
  asm("v_cvt_pk_bf16_f32 %0, %1, %2" : "=v"(d) : "v"(lo), "v"(hi));
  return d;
}

// ---------- split_T tile helper: W[K][N] 64x64 tile -> Bt[N][K] hi/lo -------
__device__ __forceinline__ void split_T_tile(const float* __restrict__ W,
    u16* __restrict__ BtH, u16* __restrict__ BtL, int K, int N, int k0, int n0,
    int t, float (*T)[65]) {
  const int r = t >> 4, c = (t & 15) * 4;
#pragma unroll
  for (int p = 0; p < 4; ++p) {
    float4 v = *(const float4*)&W[(size_t)(k0 + p * 16 + r) * N + n0 + c];
    T[p * 16 + r][c + 0] = v.x; T[p * 16 + r][c + 1] = v.y;
    T[p * 16 + r][c + 2] = v.z; T[p * 16 + r][c + 3] = v.w;
  }
  __syncthreads();
  const int rr = t >> 2, cc0 = (t & 3) * 16;
#pragma unroll
  for (int i4 = 0; i4 < 4; ++i4) {
    float f0 = T[cc0 + i4 * 4 + 0][rr];
    float f1 = T[cc0 + i4 * 4 + 1][rr];
    float f2 = T[cc0 + i4 * 4 + 2][rr];
    float f3 = T[cc0 + i4 * 4 + 3][rr];
    ushort4 h, l;
    h.x = f2bf(f0); l.x = f2bf(f0 - bf2f(h.x));
    h.y = f2bf(f1); l.y = f2bf(f1 - bf2f(h.y));
    h.z = f2bf(f2); l.z = f2bf(f2 - bf2f(h.z));
    h.w = f2bf(f3); l.w = f2bf(f3 - bf2f(h.w));
    size_t off = (size_t)(n0 + rr) * K + k0 + cc0 + i4 * 4;
    *(ushort4*)&BtH[off] = h;
    *(ushort4*)&BtL[off] = l;
  }
}

// ---------- fused prep: splitf(x) + split_T(Wq,Wk,Wv,Wo) + bias concat ------
__global__ __launch_bounds__(256) void prep(
    const float* __restrict__ x,  const float* __restrict__ Wq,
    const float* __restrict__ Wk, const float* __restrict__ Wv,
    const float* __restrict__ Wo, const float* __restrict__ bq,
    const float* __restrict__ bk, const float* __restrict__ bv,
    u16* __restrict__ xh, u16* __restrict__ xl,
    u16* __restrict__ WqkvH, u16* __restrict__ WqkvL,
    u16* __restrict__ WoH, u16* __restrict__ WoL, float* __restrict__ bcat) {
  __shared__ float T[64][65];
  const int bx = blockIdx.x, t = threadIdx.x;
  if (bx < 3072) {                       // splitf: 786432 float4s
    int i = bx * 256 + t;
    float4 v = ((const float4*)x)[i];
    ushort4 h, l;
    h.x = f2bf(v.x); l.x = f2bf(v.x - bf2f(h.x));
    h.y = f2bf(v.y); l.y = f2bf(v.y - bf2f(h.y));
    h.z = f2bf(v.z); l.z = f2bf(v.z - bf2f(h.z));
    h.w = f2bf(v.w); l.w = f2bf(v.w - bf2f(h.w));
    ((ushort4*)xh)[i] = h;
    ((ushort4*)xl)[i] = l;
  } else if (bx < 3648) {                // Wq: 24 n-tiles x 24 k-tiles
    int b = bx - 3072;
    split_T_tile(Wq, WqkvH, WqkvL, HID, HID, (b / 24) * 64, (b % 24) * 64, t, T);
  } else if (bx < 3744) {                // Wk: 4 x 24
    int b = bx - 3648;
    split_T_tile(Wk, WqkvH + (size_t)HID * HID, WqkvL + (size_t)HID * HID,
                 HID, 256, (b / 4) * 64, (b % 4) * 64, t, T);
  } else if (bx < 3840) {                // Wv: 4 x 24
    int b = bx - 3744;
    split_T_tile(Wv, WqkvH + (size_t)(HID + 256) * HID, WqkvL + (size_t)(HID + 256) * HID,
                 HID, 256, (b / 4) * 64, (b % 4) * 64, t, T);
  } else if (bx < 4416) {                // Wo: 24 x 24
    int b = bx - 3840;
    split_T_tile(Wo, WoH, WoL, HID, HID, (b / 24) * 64, (b % 24) * 64, t, T);
  } else {                               // bias concat: 8 blocks
    int i = (bx - 4416) * 256 + t;
    bcat[i] = (i < HID) ? bq[i] : (i < HID + 256 ? bk[i - HID] : bv[i - HID - 256]);
  }
}

// ------------- bf16x3 GEMM, 128x64 tile, 4 waves, LDS-staged ----------------
// v1 structure (verified 296.9/298.3/295.2/294.2/292.4/292.8 us config):
// stage via global_load_lds w=16, linear LDS dest + source XOR-swizzle,
// serial 2-barrier K-loop. 48 KB LDS; independent blocks/CU provide the
// latency overlap (m114) that the BK=32-dbuf (v2) and 128x128 (v3) variants
// destroyed (+31/+28 us measured). No setprio: harmful on lockstep GEMM (m190).
__global__ __launch_bounds__(256, 2) void gemm3(
    const u16* __restrict__ Ah, const u16* __restrict__ Al,
    const u16* __restrict__ Bh, const u16* __restrict__ Bl,
    const float* __restrict__ bias, float* __restrict__ C,
    int K, int ldc) {
  __shared__ __align__(16) u16 sAh[128 * 64];   // 16 KB, row = 8 x 16B chunks
  __shared__ __align__(16) u16 sAl[128 * 64];   // 16 KB
  __shared__ __align__(16) u16 sBh[64 * 64];    // 8 KB
  __shared__ __align__(16) u16 sBl[64 * 64];    // 8 KB
  const int m0 = blockIdx.y * 128, n0 = blockIdx.x * 64;
  const int t = threadIdx.x, lane = t & 63, w = t >> 6;
  const int quad = lane >> 4, l15 = lane & 15;
  const int wm = w >> 1, wn = w & 1;            // wave tile: 64(M) x 32(N)
  const int l8 = lane >> 3, j8 = lane & 7;      // staging: 8 lanes per row

  f32x4 acc[4][2];
#pragma unroll
  for (int mt = 0; mt < 4; ++mt)
#pragma unroll
    for (int nt = 0; nt < 2; ++nt) acc[mt][nt] = (f32x4){0.f, 0.f, 0.f, 0.f};

  for (int k0 = 0; k0 < K; k0 += 64) {
    if (k0) __syncthreads();                    // waves done reading prev tile
#pragma unroll
    for (int i = 0; i < 4; ++i) {               // A hi/lo: 128 rows
      int r = (i * 4 + w) * 8 + l8;
      size_t goff = (size_t)(m0 + r) * K + k0 + ((j8 ^ (r & 7)) << 3);
      __builtin_amdgcn_global_load_lds(
          (const __attribute__((address_space(1))) void*)(Ah + goff),
          (__attribute__((address_space(3))) void*)&sAh[(i * 4 + w) * 512], 16, 0, 0);
      __builtin_amdgcn_global_load_lds(
          (const __attribute__((address_space(1))) void*)(Al + goff),
          (__attribute__((address_space(3))) void*)&sAl[(i * 4 + w) * 512], 16, 0, 0);
    }
#pragma unroll
    for (int i = 0; i < 2; ++i) {               // B hi/lo: 64 rows
      int r = (i * 4 + w) * 8 + l8;
      size_t goff = (size_t)(n0 + r) * K + k0 + ((j8 ^ (r & 7)) << 3);
      __builtin_amdgcn_global_load_lds(
          (const __attribute__((address_space(1))) void*)(Bh + goff),
          (__attribute__((address_space(3))) void*)&sBh[(i * 4 + w) * 512], 16, 0, 0);
      __builtin_amdgcn_global_load_lds(
          (const __attribute__((address_space(1))) void*)(Bl + goff),
          (__attribute__((address_space(3))) void*)&sBl[(i * 4 + w) * 512], 16, 0, 0);
    }
    __syncthreads();                            // compiler drains vmcnt: ready
#pragma unroll
    for (int kk = 0; kk < 2; ++kk) {
      bf16x8 aH[4], aL[4], bH[2], bL[2];
#pragma unroll
      for (int mt = 0; mt < 4; ++mt) {
        int r = wm * 64 + mt * 16 + l15;
        int addr = r * 64 + ((((kk << 2) + quad) ^ (r & 7)) << 3);
        aH[mt] = *(const bf16x8*)&sAh[addr];
        aL[mt] = *(const bf16x8*)&sAl[addr];
      }
#pragma unroll
      for (int nt = 0; nt < 2; ++nt) {
        int r = wn * 32 + nt * 16 + l15;
        int addr = r * 64 + ((((kk << 2) + quad) ^ (r & 7)) << 3);
        bH[nt] = *(const bf16x8*)&sBh[addr];
        bL[nt] = *(const bf16x8*)&sBl[addr];
      }
#pragma unroll
      for (int mt = 0; mt < 4; ++mt)
#pragma unroll
        for (int nt = 0; nt < 2; ++nt) {
          acc[mt][nt] = __builtin_amdgcn_mfma_f32_16x16x32_bf16(aH[mt], bH[nt], acc[mt][nt], 0, 0, 0);
          acc[mt][nt] = __builtin_amdgcn_mfma_f32_16x16x32_bf16(aH[mt], bL[nt], acc[mt][nt], 0, 0, 0);
          acc[mt][nt] = __builtin_amdgcn_mfma_f32_16x16x32_bf16(aL[mt], bH[nt], acc[mt][nt], 0, 0, 0);
        }
    }
  }
#pragma unroll
  for (int nt = 0; nt < 2; ++nt) {
    int col = n0 + wn * 32 + nt * 16 + l15;
    float bv = bias ? bias[col] : 0.f;
#pragma unroll
    for (int mt = 0; mt < 4; ++mt)
#pragma unroll
      for (int reg = 0; reg < 4; ++reg) {
        int row = m0 + wm * 64 + mt * 16 + quad * 4 + reg;
        C[(size_t)row * ldc + col] = acc[mt][nt][reg] + bv;
      }
  }
}

// ---------- fused post: rope_q + build_k + build_vt -------------------------
__global__ __launch_bounds__(256) void post(
    const float* __restrict__ qkv, const float* __restrict__ k_hist,
    const float* __restrict__ v_hist, const float* __restrict__ cs,
    const float* __restrict__ sn, u16* __restrict__ Qb, u16* __restrict__ Kb,
    u16* __restrict__ Vt) {
  __shared__ u16 T[64][68];
  const int bx = blockIdx.x, t = threadIdx.x;
  if (bx < 1536) {                       // rope_q: NH*QL*16 float4-pairs
    int idx = bx * 256 + t;
    int dp4 = (idx & 15) * 4;
    int q   = (idx >> 4) & 2047;
    int h   = idx >> 15;
    const float* base = qkv + (size_t)q * NQKV + h * HD;
    float4 x1 = *(const float4*)&base[dp4];
    float4 x2 = *(const float4*)&base[dp4 + 64];
    float4 c = *(const float4*)&cs[q * 64 + dp4];
    float4 s = *(const float4*)&sn[q * 64 + dp4];
    u16* ob = Qb + ((size_t)h * QL + q) * HD;
    ushort4 o1, o2;
    o1.x = f2bf((x1.x * c.x - x2.x * s.x) * QSCALE);
    o1.y = f2bf((x1.y * c.y - x2.y * s.y) * QSCALE);
    o1.z = f2bf((x1.z * c.z - x2.z * s.z) * QSCALE);
    o1.w = f2bf((x1.w * c.w - x2.w * s.w) * QSCALE);
    o2.x = f2bf((x1.x * s.x + x2.x * c.x) * QSCALE);
    o2.y = f2bf((x1.y * s.y + x2.y * c.y) * QSCALE);
    o2.z = f2bf((x1.z * s.z + x2.z * c.z) * QSCALE);
    o2.w = f2bf((x1.w * s.w + x2.w * c.w) * QSCALE);
    *(ushort4*)&ob[dp4]      = o1;
    *(ushort4*)&ob[dp4 + 64] = o2;
  } else if (bx < 2048) {                // build_k: NKVH*KLEN*16
    int idx = (bx - 1536) * 256 + t;
    int dp4 = (idx & 15) * 4;
    int tt  = (idx >> 4) & 4095;
    int kvh = idx >> 16;
    u16* ob = Kb + ((size_t)kvh * KLEN + tt) * HD;
    if (tt < HISTN) {
      const float* hb = k_hist + ((size_t)tt * NKVH + kvh) * HD;
      float4 a = *(const float4*)&hb[dp4];
      float4 b = *(const float4*)&hb[dp4 + 64];
      ushort4 o1, o2;
      o1.x = f2bf(a.x); o1.y = f2bf(a.y); o1.z = f2bf(a.z); o1.w = f2bf(a.w);
      o2.x = f2bf(b.x); o2.y = f2bf(b.y); o2.z = f2bf(b.z); o2.w = f2bf(b.w);
      *(ushort4*)&ob[dp4]      = o1;
      *(ushort4*)&ob[dp4 + 64] = o2;
    } else {
      int q = tt - HISTN;
      const float* base = qkv + (size_t)q * NQKV + HID + kvh * HD;
      float4 x1 = *(const float4*)&base[dp4];
      float4 x2 = *(const float4*)&base[dp4 + 64];
      float4 c = *(const float4*)&cs[q * 64 + dp4];
      float4 s = *(const float4*)&sn[q * 64 + dp4];
      ushort4 o1, o2;
      o1.x = f2bf(x1.x * c.x - x2.x * s.x);
      o1.y = f2bf(x1.y * c.y - x2.y * s.y);
      o1.z = f2bf(x1.z * c.z - x2.z * s.z);
      o1.w = f2bf(x1.w * c.w - x2.w * s.w);
      o2.x = f2bf(x1.x * s.x + x2.x * c.x);
      o2.y = f2bf(x1.y * s.y + x2.y * c.y);
      o2.z = f2bf(x1.z * s.z + x2.z * c.z);
      o2.w = f2bf(x1.w * s.w + x2.w * c.w);
      *(ushort4*)&ob[dp4]      = o1;
      *(ushort4*)&ob[dp4 + 64] = o2;
    }
  } else {                               // build_vt: 260 blocks
    int b = bx - 2048;
    int xt = b % 65, rest = b / 65;
    int dh = rest & 1, kvh = rest >> 1;
    if (xt == 64) {                      // rows 128..143: 128=ones, rest zero
      int r0 = 128 + dh * 8;
      u16* base = Vt + ((size_t)kvh * VTROWS) * KLEN;
      for (int i = t; i < 8192; i += 256) {
        int row = r0 + (i >> 10), c4 = (i & 1023) * 4;
        u16 v = (row == 128) ? (u16)0x3F80 : (u16)0;
        ushort4 o4 = {v, v, v, v};
        *(ushort4*)&base[(size_t)row * KLEN + c4] = o4;
      }
      return;
    }
    const int t0 = xt * 64, d0 = dh * 64;
    const int r = t >> 4, c = (t & 15) * 4;
#pragma unroll
    for (int p = 0; p < 4; ++p) {
      int tt = t0 + p * 16 + r;
      float4 v;
      if (tt < HISTN) v = *(const float4*)&v_hist[((size_t)tt * NKVH + kvh) * HD + d0 + c];
      else            v = *(const float4*)&qkv[(size_t)(tt - HISTN) * NQKV + HID + 256 + kvh * HD + d0 + c];
      T[p * 16 + r][c + 0] = f2bf(v.x); T[p * 16 + r][c + 1] = f2bf(v.y);
      T[p * 16 + r][c + 2] = f2bf(v.z); T[p * 16 + r][c + 3] = f2bf(v.w);
    }
    __syncthreads();
    const int dr = t >> 2, cc0 = (t & 3) * 16;
#pragma unroll
    for (int i4 = 0; i4 < 4; ++i4) {
      ushort4 o4;
      o4.x = T[cc0 + i4 * 4 + 0][dr];
      o4.y = T[cc0 + i4 * 4 + 1][dr];
      o4.z = T[cc0 + i4 * 4 + 2][dr];
      o4.w = T[cc0 + i4 * 4 + 3][dr];
      *(ushort4*)&Vt[((size_t)kvh * VTROWS + d0 + dr) * KLEN + t0 + cc0 + i4 * 4] = o4;
    }
  }
}

// -------- attn6: dbuf K/V staging + swapped-QK in-register softmax ----------
// Verified best (292.4/292.8/294.2/295.2 us total, attn6 ~104 us): dbuf
// prefetch, swapped-QK in-register softmax (cvt_pk + quad shuffle),
// transposed oacc for coalesced 4x64B atomics, T5 setprio on MFMA (m191).
__global__ __launch_bounds__(384, 3) void attn6(
    const u16* __restrict__ Q, const u16* __restrict__ K,
    const u16* __restrict__ Vt, float* __restrict__ oacc) {
  __shared__ __align__(16) u16 sK[2][64 * 128];  // 2 x 16 KB, swizzled
  __shared__ __align__(16) u16 sV[2][128 * 64];  // 2 x 16 KB, swizzled (rows=d)
  const int bid = blockIdx.x;
  const int kvh   = (bid >> 2) & 1;
  const int qs    = (bid & 3) | ((bid >> 3) << 2);   // 0..255
  const int qt    = qs >> 2, slice = qs & 3;
  const int q0 = qt * 32;
  const int t = threadIdx.x, lane = t & 63, w = t / 64;   // w = head-in-group
  const int h = kvh * 6 + w;
  const int quad = lane >> 4, l15 = lane & 15, q8 = quad * 8;

  const u16* Qg = Q + ((size_t)h * QL + q0) * HD;
  bf16x8 Qf[2][4];
#pragma unroll
  for (int mt = 0; mt < 2; ++mt)
#pragma unroll
    for (int dc = 0; dc < 4; ++dc)
      Qf[mt][dc] = *(const bf16x8*)&Qg[(mt * 16 + l15) * HD + dc * 32 + q8];

  const int nsteps = (q0 + 32 + HISTN + 63) >> 6;
  const int bas = nsteps >> 2, rem = nsteps & 3;
  const int cnt = bas + (slice < rem ? 1 : 0);
  const int s0  = slice * bas + (slice < rem ? slice : rem);

  f32x4 o[2][8];
  float lp[2] = {0.f, 0.f};
#pragma unroll
  for (int mt = 0; mt < 2; ++mt)
#pragma unroll
    for (int dt = 0; dt < 8; ++dt) o[mt][dt] = (f32x4){0.f, 0.f, 0.f, 0.f};

  const u16* Kh = K + (size_t)kvh * KLEN * HD;
  const u16* Vh = Vt + (size_t)kvh * VTROWS * KLEN;
  const int x7 = l15 & 7;

  auto STAGE = [&](int b, int k0) {
    for (int i = w; i < 32; i += 6) {
      if (i < 16) {
        int r = 4 * i + (lane >> 4);        // K row 0..63
        int c = lane & 15;                  // 16B chunk 0..15
        const u16* src = Kh + (size_t)(k0 + r) * HD + ((c ^ (r & 7)) << 3);
        __builtin_amdgcn_global_load_lds(
            (const __attribute__((address_space(1))) void*)src,
            (__attribute__((address_space(3))) void*)&sK[b][i * 512], 16, 0, 0);
      } else {
        int j = i - 16;
        int r = 8 * j + (lane >> 3);        // V d-row 0..127
        int c = lane & 7;                   // 16B chunk 0..7
        const u16* src = Vh + (size_t)r * KLEN + k0 + ((c ^ (r & 7)) << 3);
        __builtin_amdgcn_global_load_lds(
            (const __attribute__((address_space(1))) void*)src,
            (__attribute__((address_space(3))) void*)&sV[b][j * 512], 16, 0, 0);
      }
    }
  };

  int cur = 0;
  STAGE(0, s0 << 6);
  __syncthreads();     // prologue drain: tile s0 ready

  for (int s = s0; s < s0 + cnt; ++s) {
    const int k0 = s << 6;
    if (s + 1 < s0 + cnt) STAGE(cur ^ 1, (s + 1) << 6);   // prefetch next
    f32x4 sc[2][4];
#pragma unroll
    for (int mt = 0; mt < 2; ++mt)
#pragma unroll
      for (int kt = 0; kt < 4; ++kt) sc[mt][kt] = (f32x4){0.f, 0.f, 0.f, 0.f};
    __builtin_amdgcn_s_setprio(1);   // T5: favor this wave during QK MFMA
#pragma unroll
    for (int dc = 0; dc < 4; ++dc) {
      bf16x8 bK[4];
#pragma unroll
      for (int kt = 0; kt < 4; ++kt)
        bK[kt] = *(const bf16x8*)&sK[cur][(kt * 16 + l15) * 128 + (((dc * 4 + quad) ^ x7) << 3)];
#pragma unroll
      for (int mt = 0; mt < 2; ++mt)
#pragma unroll
        for (int kt = 0; kt < 4; ++kt)
          sc[mt][kt] = __builtin_amdgcn_mfma_f32_16x16x32_bf16(bK[kt], Qf[mt][dc], sc[mt][kt], 0, 0, 0);
    }
    __builtin_amdgcn_s_setprio(0);   // back to normal for VALU phase
    if (k0 + 63 - HISTN > q0) {   // causal boundary inside this step
#pragma unroll
      for (int mt = 0; mt < 2; ++mt)
#pragma unroll
        for (int kt = 0; kt < 4; ++kt) {
#pragma unroll
          for (int reg = 0; reg < 4; ++reg) {
            int kg = k0 + kt * 16 + quad * 4 + reg;
            if (kg > q0 + mt * 16 + l15 + HISTN) sc[mt][kt][reg] = -INFINITY;
          }
        }
    }
#pragma unroll
    for (int mt = 0; mt < 2; ++mt)
#pragma unroll
      for (int kt = 0; kt < 4; ++kt)
#pragma unroll
        for (int reg = 0; reg < 4; ++reg) {
          float p = __expf(sc[mt][kt][reg]);
          sc[mt][kt][reg] = p;
          lp[mt] += p;
        }
#pragma unroll
    for (int kc = 0; kc < 2; ++kc) {
      bf16x8 pP[2];
#pragma unroll
      for (int mt = 0; mt < 2; ++mt) {
        const f32x4 pa = sc[mt][kc * 2];
        const f32x4 pb = sc[mt][kc * 2 + 1];
        unsigned A0 = cvt_pk_bf16(pa[0], pa[1]);
        unsigned A1 = cvt_pk_bf16(pa[2], pa[3]);
        unsigned B0 = cvt_pk_bf16(pb[0], pb[1]);
        unsigned B1 = cvt_pk_bf16(pb[2], pb[3]);
        bool hiQ = quad >= 2;
        unsigned s16a = hiQ ? B0 : A0, s16b = hiQ ? B1 : A1;
        unsigned s3a  = hiQ ? A0 : B0, s3b  = hiQ ? A1 : B1;
        unsigned r16a = __shfl_xor(s16a, 16), r16b = __shfl_xor(s16b, 16);
        unsigned r32a = __shfl_xor(s3a, 32),  r32b = __shfl_xor(s3b, 32);
        unsigned r48a = __shfl_xor(s3a, 48),  r48b = __shfl_xor(s3b, 48);
        union { unsigned u[4]; bf16x8 v; } P;
        P.u[0] = quad == 0 ? A0 : quad == 1 ? r48a : quad == 2 ? r32a : r16a;
        P.u[1] = quad == 0 ? A1 : quad == 1 ? r48b : quad == 2 ? r32b : r16b;
        P.u[2] = quad == 0 ? r16a : quad == 1 ? r32a : quad == 2 ? r48a : B0;
        P.u[3] = quad == 0 ? r16b : quad == 1 ? r32b : quad == 2 ? r48b : B1;
        pP[mt] = P.v;
      }
      __builtin_amdgcn_s_setprio(1);   // T5: favor this wave during PV MFMA
#pragma unroll
      for (int dt = 0; dt < 8; ++dt) {
        bf16x8 bV = *(const bf16x8*)&sV[cur][(dt * 16 + l15) * 64 + (((kc * 4 + quad) ^ x7) << 3)];
#pragma unroll
        for (int mt = 0; mt < 2; ++mt)
          o[mt][dt] = __builtin_amdgcn_mfma_f32_16x16x32_bf16(bV, pP[mt], o[mt][dt], 0, 0, 0);
      }
      __builtin_amdgcn_s_setprio(0);
    }
    __syncthreads();   // all waves done with tile cur; prefetch drained+visible
    cur ^= 1;
  }

  // ---- accumulate partials: oacc[h][dv][q] -> coalesced 4x64B per instr ----
  float* ob = oacc + (size_t)h * 132 * QL + q0;
#pragma unroll
  for (int mt = 0; mt < 2; ++mt) {
    lp[mt] += __shfl_xor(lp[mt], 16);
    lp[mt] += __shfl_xor(lp[mt], 32);
    int qc = mt * 16 + l15;
#pragma unroll
    for (int dt = 0; dt < 8; ++dt)
#pragma unroll
      for (int reg = 0; reg < 4; ++reg)
        atomicAdd(&ob[(size_t)(dt * 16 + quad * 4 + reg) * QL + qc], o[mt][dt][reg]);
    if (quad == 0) atomicAdd(&ob[(size_t)128 * QL + qc], lp[mt]);
  }
}

// ---------- attn_norm: LDS transpose [h][dv][q] -> attn[q][HID], /l ---------
__global__ __launch_bounds__(256) void attn_norm(const float* __restrict__ oacc,
    u16* __restrict__ OH, u16* __restrict__ OL) {
  __shared__ float T2[128][33];
  __shared__ float linv[32];
  const int h  = blockIdx.x >> 6;              // 12 x 64 blocks
  const int q0 = (blockIdx.x & 63) * 32;
  const int t  = threadIdx.x;
  const float* base = oacc + (size_t)h * 132 * QL + q0;
  const int col = t & 31, r0 = t >> 5;         // 8 rows per pass, coalesced
#pragma unroll
  for (int pass = 0; pass < 16; ++pass) {
    int row = pass * 8 + r0;
    T2[row][col] = base[(size_t)row * QL + col];
  }
  if (t < 32) linv[t] = 1.f / base[(size_t)128 * QL + t];
  __syncthreads();
  const int ql = t >> 3, d0 = (t & 7) * 16;
  float inv = linv[ql];
  size_t ob = (size_t)(q0 + ql) * HID + h * HD + d0;
#pragma unroll
  for (int j = 0; j < 16; ++j) {
    float val = T2[d0 + j][ql] * inv;
    u16 hv = f2bf(val);
    OH[ob + j] = hv;
    OL[ob + j] = f2bf(val - bf2f(hv));
  }
}

extern "C" void kernel_launch(void* const* d_in, const int* in_sizes, int n_in,
                              void* d_out, int out_size, void* d_ws, size_t ws_size,
                              hipStream_t stream) {
  (void)in_sizes; (void)n_in; (void)out_size; (void)ws_size;
  const float* x      = (const float*)d_in[0];
  const float* Wq     = (const float*)d_in[1];
  const float* bq     = (const float*)d_in[2];
  const float* Wk     = (const float*)d_in[3];
  const float* bk     = (const float*)d_in[4];
  const float* Wv     = (const float*)d_in[5];
  const float* bv     = (const float*)d_in[6];
  const float* Wo     = (const float*)d_in[7];
  const float* k_hist = (const float*)d_in[8];
  const float* v_hist = (const float*)d_in[9];
  const float* fcos   = (const float*)d_in[10];
  const float* fsin   = (const float*)d_in[11];
  float* out = (float*)d_out;

  char* p = (char*)d_ws;
  float* qkv   = (float*)p;  p += (size_t)QL * NQKV * 4;            // 16.78 MB
  u16*   Qb    = (u16*)p;    p += (size_t)NH * QL * HD * 2;
  u16*   Kb    = (u16*)p;    p += (size_t)NKVH * KLEN * HD * 2;
  u16*   Vtb   = (u16*)p;    p += (size_t)NKVH * VTROWS * KLEN * 2;
  u16*   xh    = (u16*)p;    p += (size_t)QL * HID * 2;             // alias attnH
  u16*   xl    = (u16*)p;    p += (size_t)QL * HID * 2;             // alias attnL
  u16*   WqkvH = (u16*)p;    p += (size_t)NQKV * HID * 2;
  u16*   WqkvL = (u16*)p;    p += (size_t)NQKV * HID * 2;
  u16*   WoH   = (u16*)p;    p += (size_t)HID * HID * 2;
  u16*   WoL   = (u16*)p;    p += (size_t)HID * HID * 2;
  float* bcat  = (float*)p;  p += (size_t)NQKV * 4;                 // ~64 MB total
  u16* attnH = xh;  u16* attnL = xl;    // x dead after QKV gemm
  float* oacc = qkv;                    // qkv dead after post; 12x132x2048 f32

  prep<<<4424, 256, 0, stream>>>(x, Wq, Wk, Wv, Wo, bq, bk, bv,
                                 xh, xl, WqkvH, WqkvL, WoH, WoL, bcat);
  gemm3<<<dim3(NQKV / 64, QL / 128), 256, 0, stream>>>(xh, xl, WqkvH, WqkvL, bcat, qkv, HID, NQKV);
  post<<<2308, 256, 0, stream>>>(qkv, k_hist, v_hist, fcos, fsin, Qb, Kb, Vtb);
  hipMemsetAsync(oacc, 0, (size_t)NH * 132 * QL * 4, stream);
  attn6<<<512, 384, 0, stream>>>(Qb, Kb, Vtb, oacc);
  attn_norm<<<768, 256, 0, stream>>>(oacc, attnH, attnL);
  gemm3<<<dim3(HID / 64, QL / 128), 256, 0, stream>>>(attnH, attnL, WoH, WoL, nullptr, out, HID, HID);
}